// Round 8
// baseline (337.438 us; speedup 1.0000x reference)
//
#include <hip/hip_runtime.h>
#include <math.h>

#define IN_NODES  4096
#define OUT_NODES 1024
#define ROW_ELEMS 16384          // floats per in-node row
#define ROW_C4    4096           // float4 chunks per row
#define ROW_U4    2048           // uint4 (8xbf16) chunks per row
#define NG        256            // grid
#define PB        16             // rows per block (4096/256)

typedef unsigned short u16;
typedef unsigned int   u32;

__device__ __forceinline__ float dot4(const float4 a, const float4 b) {
    return a.x*b.x + a.y*b.y + a.z*b.z + a.w*b.w;
}
__device__ __forceinline__ void fma4(float4& a, const float c, const float4 u) {
    a.x += c*u.x; a.y += c*u.y; a.z += c*u.z; a.w += c*u.w;
}
__device__ __forceinline__ void add4(float4& a, const float4 u) {
    a.x += u.x; a.y += u.y; a.z += u.z; a.w += u.w;
}
__device__ __forceinline__ u16 f2b(float x) {            // RNE f32->bf16
    u32 b = __float_as_uint(x);
    return (u16)((b + 0x7FFFu + ((b >> 16) & 1u)) >> 16);
}
__device__ __forceinline__ ushort4 f2b4(float4 v) {
    ushort4 r; r.x = f2b(v.x); r.y = f2b(v.y); r.z = f2b(v.z); r.w = f2b(v.w);
    return r;
}
// uint4 = 8 bf16 (memory order) -> two float4
__device__ __forceinline__ void unpack8(const uint4 w, float4& lo, float4& hi) {
    lo.x = __uint_as_float(w.x << 16);
    lo.y = __uint_as_float(w.x & 0xFFFF0000u);
    lo.z = __uint_as_float(w.y << 16);
    lo.w = __uint_as_float(w.y & 0xFFFF0000u);
    hi.x = __uint_as_float(w.z << 16);
    hi.y = __uint_as_float(w.z & 0xFFFF0000u);
    hi.z = __uint_as_float(w.w << 16);
    hi.w = __uint_as_float(w.w & 0xFFFF0000u);
}

// ---------------------------------------------------------------------------
// K0: uniform pass (c = 1/1024) + bf16 copy. 256 blocks x 1024 thr, no
// barriers, ~45 VGPR, fully coalesced. (Unchanged from R6 — memory-bound.)
// ---------------------------------------------------------------------------
__global__ __launch_bounds__(1024) void k_uniform(const float* __restrict__ uh,
                                                  u16* __restrict__ uh2,
                                                  float* __restrict__ part) {
    const int t    = threadIdx.x;
    const int wave = t >> 6;
    const int lane = t & 63;
    const int c0   = (wave << 8) + lane;

    float4 acc[4];
    #pragma unroll
    for (int j = 0; j < 4; ++j) acc[j] = make_float4(0.f, 0.f, 0.f, 0.f);

    const float4* p = reinterpret_cast<const float4*>(uh)
                    + (size_t)blockIdx.x * PB * ROW_C4 + c0;
    ushort4* q = reinterpret_cast<ushort4*>(uh2)
               + (size_t)blockIdx.x * PB * ROW_C4 + c0;

    for (int g = 0; g < PB; ++g) {
        float4 u[4];
        #pragma unroll
        for (int j = 0; j < 4; ++j) u[j] = p[j * 64];
        #pragma unroll
        for (int j = 0; j < 4; ++j) { add4(acc[j], u[j]); q[j * 64] = f2b4(u[j]); }
        p += ROW_C4; q += ROW_C4;
    }

    const float c = 1.0f / OUT_NODES;
    float4* sp = reinterpret_cast<float4*>(part) + (size_t)blockIdx.x * ROW_C4 + c0;
    #pragma unroll
    for (int j = 0; j < 4; ++j) {
        acc[j].x *= c; acc[j].y *= c; acc[j].z *= c; acc[j].w *= c;
        sp[j * 64] = acc[j];
    }
}

// ---------------------------------------------------------------------------
// K_soft2: one softmax pass, TWO barriers total.
//  Prologue: cooperative V -> LDS (64 KB).                       [barrier]
//  Sweep A : wave w autonomously computes row (blk*16+w)'s softmax
//            denominator: 32 coalesced uint4 chunks, V from LDS
//            (stride-32B = free 2-way banking), pair-shfl completes d[o],
//            in-wave butterfly reduce -> invD[w] in LDS.         [barrier]
//  Sweep B : barrier-free coalesced accumulation. Thread owns uint4 units
//            t and t+1024; per row: load (L2/L3-hot, just read in sweep A),
//            dot, pair-shfl, exp * invD[g] (LDS broadcast), FMA into regs.
//            ~70 VGPR, distance-1 prefetch, no LDS writes, no barriers.
// Numerically identical to R6's pass (f32 partials, same pairing).
// ---------------------------------------------------------------------------
__global__ __launch_bounds__(1024) void k_soft2(const u16* __restrict__ uh2,
                                                const float* __restrict__ V,
                                                float* __restrict__ part) {
    const int t    = threadIdx.x;
    const int wave = t >> 6;
    const int lane = t & 63;

    __shared__ float Vl[ROW_ELEMS];      // 64 KB
    __shared__ float invD[PB];

    {
        const float4* vp = reinterpret_cast<const float4*>(V);
        float4* vl = reinterpret_cast<float4*>(Vl);
        #pragma unroll
        for (int j = 0; j < 4; ++j) vl[j * 1024 + t] = vp[j * 1024 + t];
    }
    __syncthreads();

    // ---- Sweep A: per-wave denominator for row blk*PB + wave --------------
    {
        const uint4* row = reinterpret_cast<const uint4*>(uh2)
                         + (size_t)(blockIdx.x * PB + wave) * ROW_U4;
        float den = 0.f;
        #pragma unroll 4
        for (int k = 0; k < 32; ++k) {
            const int u = k * 64 + lane;
            const uint4 w = row[u];
            const float4* vv = reinterpret_cast<const float4*>(Vl + u * 8);
            float4 lo, hi;
            unpack8(w, lo, hi);
            float d = dot4(lo, vv[0]) + dot4(hi, vv[1]);
            d += __shfl_xor(d, 1);           // pair completes d[o]
            den += __expf(d);                // each o counted twice per pair
        }
        #pragma unroll
        for (int off = 32; off; off >>= 1) den += __shfl_xor(den, off);
        if (lane == 0) invD[wave] = 2.0f / den;
    }
    __syncthreads();

    // ---- Sweep B: barrier-free accumulation -------------------------------
    float4 v0a = *reinterpret_cast<const float4*>(Vl + t * 8);
    float4 v0b = *reinterpret_cast<const float4*>(Vl + t * 8 + 4);
    float4 v1a = *reinterpret_cast<const float4*>(Vl + (t + 1024) * 8);
    float4 v1b = *reinterpret_cast<const float4*>(Vl + (t + 1024) * 8 + 4);

    float4 a0 = make_float4(0.f, 0.f, 0.f, 0.f), a1 = a0, a2 = a0, a3 = a0;

    const uint4* base = reinterpret_cast<const uint4*>(uh2)
                      + (size_t)blockIdx.x * PB * ROW_U4;
    uint4 c0 = base[t], c1 = base[1024 + t];

    for (int g = 0; g < PB; ++g) {
        uint4 n0, n1;
        const uint4* nb = base + (size_t)(g + 1) * ROW_U4;
        if (g + 1 < PB) { n0 = nb[t]; n1 = nb[1024 + t]; }

        const float iD = invD[g];
        float4 lo0, hi0, lo1, hi1;
        unpack8(c0, lo0, hi0);
        unpack8(c1, lo1, hi1);
        float d0 = dot4(lo0, v0a) + dot4(hi0, v0b);
        float d1 = dot4(lo1, v1a) + dot4(hi1, v1b);
        d0 += __shfl_xor(d0, 1);
        d1 += __shfl_xor(d1, 1);
        const float e0 = __expf(d0) * iD;
        const float e1 = __expf(d1) * iD;
        fma4(a0, e0, lo0); fma4(a1, e0, hi0);
        fma4(a2, e1, lo1); fma4(a3, e1, hi1);

        c0 = n0; c1 = n1;
    }

    float4* sp = reinterpret_cast<float4*>(part) + (size_t)blockIdx.x * ROW_C4;
    sp[2 * t]              = a0;
    sp[2 * t + 1]          = a1;
    sp[2 * (1024 + t)]     = a2;
    sp[2 * (1024 + t) + 1] = a3;
}

// ---------------------------------------------------------------------------
// Reduce partials -> s, squash -> v, out, cumulative V. (Unchanged.)
// ---------------------------------------------------------------------------
__global__ __launch_bounds__(256) void k_reduce(const float* __restrict__ part,
                                                float* __restrict__ V,
                                                float* __restrict__ out,
                                                int G, int first) {
    const int t    = threadIdx.x;
    const int gidx = blockIdx.x * 64 + (t >> 2);   // o*16 + f
    const int q    = t & 3;
    const float* p = part + gidx;
    float a0 = 0.f, a1 = 0.f;
    int b = q;
    for (; b + 4 < G; b += 8) {
        a0 += p[(size_t)(b    ) * ROW_ELEMS];
        a1 += p[(size_t)(b + 4) * ROW_ELEMS];
    }
    for (; b < G; b += 4) a0 += p[(size_t)b * ROW_ELEMS];
    float s = a0 + a1;
    s += __shfl_xor(s, 1);
    s += __shfl_xor(s, 2);

    float sq = s * s;
    sq += __shfl_xor(sq, 4);
    sq += __shfl_xor(sq, 8);
    sq += __shfl_xor(sq, 16);
    sq += __shfl_xor(sq, 32);

    const float scale = sq / ((1.0f + sq) * sqrtf(sq));
    const float v = s * scale;

    out[gidx] = v;
    V[gidx]   = first ? v : (V[gidx] + v);
}

// ===========================================================================
// f32 fallback (only if workspace is unexpectedly small): R6-style kernels.
// ===========================================================================
__global__ __launch_bounds__(1024) void fb_uniform(const float* __restrict__ uh,
                                                   float* __restrict__ part,
                                                   int per_block) {
    const int t  = threadIdx.x;
    const int c0 = ((t >> 6) << 8) + (t & 63);
    float4 acc[4];
    #pragma unroll
    for (int j = 0; j < 4; ++j) acc[j] = make_float4(0.f, 0.f, 0.f, 0.f);
    const float4* p = reinterpret_cast<const float4*>(uh)
                    + (size_t)blockIdx.x * per_block * ROW_C4 + c0;
    for (int g = 0; g < per_block; ++g) {
        #pragma unroll
        for (int j = 0; j < 4; ++j) add4(acc[j], p[j * 64]);
        p += ROW_C4;
    }
    const float c = 1.0f / OUT_NODES;
    float4* sp = reinterpret_cast<float4*>(part) + (size_t)blockIdx.x * ROW_C4 + c0;
    #pragma unroll
    for (int j = 0; j < 4; ++j) {
        acc[j].x *= c; acc[j].y *= c; acc[j].z *= c; acc[j].w *= c;
        sp[j * 64] = acc[j];
    }
}

__global__ __launch_bounds__(1024) void fb_soft(const float* __restrict__ uh,
                                                const float* __restrict__ V,
                                                float* __restrict__ part,
                                                int per_block) {
    const int t    = threadIdx.x;
    const int wave = t >> 6;
    const int lane = t & 63;
    const int c0   = (wave << 8) + lane;
    __shared__ float red16[16];
    __shared__ float redS;

    float4 v[4];
    const float4* vp = reinterpret_cast<const float4*>(V) + c0;
    #pragma unroll
    for (int j = 0; j < 4; ++j) v[j] = vp[j * 64];

    float4 acc[4];
    #pragma unroll
    for (int j = 0; j < 4; ++j) acc[j] = make_float4(0.f, 0.f, 0.f, 0.f);

    const float4* p = reinterpret_cast<const float4*>(uh)
                    + (size_t)blockIdx.x * per_block * ROW_C4 + c0;
    for (int g = 0; g < per_block; ++g) {
        float4 u[4];
        #pragma unroll
        for (int j = 0; j < 4; ++j) u[j] = p[j * 64];
        float d[4];
        #pragma unroll
        for (int j = 0; j < 4; ++j) d[j] = dot4(u[j], v[j]);
        #pragma unroll
        for (int j = 0; j < 4; ++j) {
            d[j] += __shfl_xor(d[j], 1);
            d[j] += __shfl_xor(d[j], 2);
        }
        float e[4];
        float etot = 0.f;
        #pragma unroll
        for (int j = 0; j < 4; ++j) { e[j] = __expf(d[j]); etot += e[j]; }
        #pragma unroll
        for (int off = 32; off; off >>= 1) etot += __shfl_xor(etot, off);
        if (lane == 0) red16[wave] = etot;
        __syncthreads();
        if (wave == 0) {
            float s = (lane < 16) ? red16[lane] : 0.f;
            #pragma unroll
            for (int off = 8; off; off >>= 1) s += __shfl_xor(s, off);
            if (lane == 0) redS = s;
        }
        __syncthreads();
        const float inv = 4.0f / redS;
        #pragma unroll
        for (int j = 0; j < 4; ++j) fma4(acc[j], e[j] * inv, u[j]);
        p += ROW_C4;
    }
    float4* sp = reinterpret_cast<float4*>(part) + (size_t)blockIdx.x * ROW_C4 + c0;
    #pragma unroll
    for (int j = 0; j < 4; ++j) sp[j * 64] = acc[j];
}

// ---------------------------------------------------------------------------
extern "C" void kernel_launch(void* const* d_in, const int* in_sizes, int n_in,
                              void* d_out, int out_size, void* d_ws, size_t ws_size,
                              hipStream_t stream) {
    const float* uh  = (const float*)d_in[0];
    float*       out = (float*)d_out;

    char*  ws   = (char*)d_ws;
    float* V    = (float*)ws;                              // 64 KB
    float* part = (float*)(ws + 65536);                    // 256*64KB = 16 MB
    u16*   uh2  = (u16*)(ws + 65536 + (size_t)NG * ROW_ELEMS * 4);  // 128 MB

    const size_t need = 65536ull + (size_t)NG * ROW_ELEMS * 4ull
                      + (size_t)IN_NODES * ROW_ELEMS * 2ull;

    if (ws_size >= need) {
        k_uniform<<<NG, 1024, 0, stream>>>(uh, uh2, part);
        k_reduce<<<256, 256, 0, stream>>>(part, V, out, NG, 1);
        for (int it = 1; it < 3; ++it) {
            k_soft2<<<NG, 1024, 0, stream>>>(uh2, V, part);
            k_reduce<<<256, 256, 0, stream>>>(part, V, out, NG, 0);
        }
    } else {
        int G2 = 256;
        while (G2 > 4 && ws_size < 65536ull * (size_t)(G2 + 1)) G2 >>= 1;
        const int per_block = IN_NODES / G2;
        fb_uniform<<<G2, 1024, 0, stream>>>(uh, part, per_block);
        k_reduce<<<256, 256, 0, stream>>>(part, V, out, G2, 1);
        for (int it = 1; it < 3; ++it) {
            fb_soft<<<G2, 1024, 0, stream>>>(uh, V, part, per_block);
            k_reduce<<<256, 256, 0, stream>>>(part, V, out, G2, 0);
        }
    }
}

// Round 9
// 309.561 us; speedup vs baseline: 1.0901x; 1.0901x over previous
//
#include <hip/hip_runtime.h>
#include <hip/hip_cooperative_groups.h>
#include <math.h>

namespace cg = cooperative_groups;

#define IN_NODES  4096
#define OUT_NODES 1024
#define ROW_ELEMS 16384          // floats per in-node row
#define ROW_C4    4096           // float4 chunks per row
#define ROW_U4    2048           // uint4 (8xbf16) chunks per row
#define NG        256            // grid
#define PB        16             // rows per block (4096/256)

typedef unsigned short u16;
typedef unsigned int   u32;

__device__ __forceinline__ float dot4(const float4 a, const float4 b) {
    return a.x*b.x + a.y*b.y + a.z*b.z + a.w*b.w;
}
__device__ __forceinline__ void fma4(float4& a, const float c, const float4 u) {
    a.x += c*u.x; a.y += c*u.y; a.z += c*u.z; a.w += c*u.w;
}
__device__ __forceinline__ void add4(float4& a, const float4 u) {
    a.x += u.x; a.y += u.y; a.z += u.z; a.w += u.w;
}
__device__ __forceinline__ u16 f2b(float x) {            // RNE f32->bf16
    u32 b = __float_as_uint(x);
    return (u16)((b + 0x7FFFu + ((b >> 16) & 1u)) >> 16);
}
__device__ __forceinline__ ushort4 f2b4(float4 v) {
    ushort4 r; r.x = f2b(v.x); r.y = f2b(v.y); r.z = f2b(v.z); r.w = f2b(v.w);
    return r;
}
// uint4 = 8 bf16 (memory order) -> two float4
__device__ __forceinline__ void unpack8(const uint4 w, float4& lo, float4& hi) {
    lo.x = __uint_as_float(w.x << 16);
    lo.y = __uint_as_float(w.x & 0xFFFF0000u);
    lo.z = __uint_as_float(w.y << 16);
    lo.w = __uint_as_float(w.y & 0xFFFF0000u);
    hi.x = __uint_as_float(w.z << 16);
    hi.y = __uint_as_float(w.z & 0xFFFF0000u);
    hi.z = __uint_as_float(w.w << 16);
    hi.w = __uint_as_float(w.w & 0xFFFF0000u);
}

// ===========================================================================
// FUSED cooperative kernel: 256 blocks x 1024 thr (16 waves/CU, same
// occupancy as the proven R6 kernels). Phase bodies are verbatim R6 code;
// grid.sync() replaces kernel boundaries. Reduce is distributed: block owns
// 64 consecutive floats of s/V; wave0 squashes and writes V (grid.sync
// propagates it — pattern proven correct in the R5 fused kernel).
// ===========================================================================
__global__ __launch_bounds__(1024)
void fused_route(const float* __restrict__ uh, u16* __restrict__ uh2,
                 float* __restrict__ part, float* __restrict__ V,
                 float* __restrict__ out) {
    cg::grid_group grid = cg::this_grid();
    const int t    = threadIdx.x;
    const int wave = t >> 6;
    const int lane = t & 63;
    const int blk  = blockIdx.x;

    __shared__ float2 red16[16];
    __shared__ float2 redS;
    __shared__ float  sred[16][64];

    // ---------------- P0: uniform pass + bf16 copy (R6 k_uniform) ---------
    {
        const int c0 = (wave << 8) + lane;
        float4 acc[4];
        #pragma unroll
        for (int j = 0; j < 4; ++j) acc[j] = make_float4(0.f, 0.f, 0.f, 0.f);

        const float4* p = reinterpret_cast<const float4*>(uh)
                        + (size_t)blk * PB * ROW_C4 + c0;
        ushort4* q = reinterpret_cast<ushort4*>(uh2)
                   + (size_t)blk * PB * ROW_C4 + c0;

        for (int g = 0; g < PB; ++g) {
            float4 u[4];
            #pragma unroll
            for (int j = 0; j < 4; ++j) u[j] = p[j * 64];
            #pragma unroll
            for (int j = 0; j < 4; ++j) { add4(acc[j], u[j]); q[j * 64] = f2b4(u[j]); }
            p += ROW_C4; q += ROW_C4;
        }

        const float c = 1.0f / OUT_NODES;
        float4* sp = reinterpret_cast<float4*>(part) + (size_t)blk * ROW_C4 + c0;
        #pragma unroll
        for (int j = 0; j < 4; ++j) {
            acc[j].x *= c; acc[j].y *= c; acc[j].z *= c; acc[j].w *= c;
            sp[j * 64] = acc[j];
        }
    }
    grid.sync();

    // ---------------- iterations: reduce -> (softmax pass) -----------------
    for (int it = 0; it < 3; ++it) {
        // ---- R(it): distributed reduce + squash; block owns 64 floats ----
        {
            const float* pp = part + blk * 64 + lane;
            float s0 = 0.f, s1 = 0.f;
            for (int b = wave; b < NG; b += 32) {
                s0 += pp[(size_t)b * ROW_ELEMS];
                s1 += pp[(size_t)(b + 16) * ROW_ELEMS];
            }
            sred[wave][lane] = s0 + s1;
            __syncthreads();
            if (wave == 0) {
                float s = 0.f;
                #pragma unroll
                for (int w = 0; w < 16; ++w) s += sred[w][lane];
                float sq = s * s;             // out-node = 16-lane group
                sq += __shfl_xor(sq, 1);
                sq += __shfl_xor(sq, 2);
                sq += __shfl_xor(sq, 4);
                sq += __shfl_xor(sq, 8);
                const float scale = sq / ((1.0f + sq) * sqrtf(sq));
                const float v = s * scale;
                const int g = blk * 64 + lane;
                V[g] = (it == 0) ? v : (V[g] + v);
                if (it == 2) out[g] = v;
            }
        }
        if (it == 2) break;
        grid.sync();

        // ---- P(it+1): softmax pass over bf16 copy (R6 k_soft, verbatim) --
        {
            const int u0 = (wave << 7) + lane;
            float4 v[4];
            {
                const float4* vp = reinterpret_cast<const float4*>(V);
                v[0] = vp[2 * u0];          v[1] = vp[2 * u0 + 1];
                v[2] = vp[2 * (u0 + 64)];   v[3] = vp[2 * (u0 + 64) + 1];
            }

            float4 acc[4];
            #pragma unroll
            for (int j = 0; j < 4; ++j) acc[j] = make_float4(0.f, 0.f, 0.f, 0.f);

            const uint4* p = reinterpret_cast<const uint4*>(uh2)
                           + (size_t)blk * PB * ROW_U4 + u0;

            uint4 cur[4];
            cur[0] = p[0];      cur[1] = p[64];
            cur[2] = p[ROW_U4]; cur[3] = p[ROW_U4 + 64];

            for (int g = 0; g < PB; g += 2) {
                uint4 nxt[4];
                const uint4* pn = p + 2 * ROW_U4;
                if (g + 2 < PB) {
                    nxt[0] = pn[0];      nxt[1] = pn[64];
                    nxt[2] = pn[ROW_U4]; nxt[3] = pn[ROW_U4 + 64];
                }

                float d[4];
                #pragma unroll
                for (int j = 0; j < 4; ++j) {
                    float4 lo, hi;
                    unpack8(cur[j], lo, hi);
                    d[j] = dot4(lo, v[(j & 1) * 2]) + dot4(hi, v[(j & 1) * 2 + 1]);
                }
                #pragma unroll
                for (int j = 0; j < 4; ++j) d[j] += __shfl_xor(d[j], 1);

                float e[4];
                #pragma unroll
                for (int j = 0; j < 4; ++j) e[j] = __expf(d[j]);

                float ea = e[0] + e[1];     // row a (each o counted 2x)
                float eb = e[2] + e[3];     // row b
                #pragma unroll
                for (int off = 32; off; off >>= 1) {
                    ea += __shfl_xor(ea, off);
                    eb += __shfl_xor(eb, off);
                }
                if (lane == 0) red16[wave] = make_float2(ea, eb);
                __syncthreads();
                if (wave == 0) {
                    float2 qv = (lane < 16) ? red16[lane] : make_float2(0.f, 0.f);
                    #pragma unroll
                    for (int off = 8; off; off >>= 1) {
                        qv.x += __shfl_xor(qv.x, off);
                        qv.y += __shfl_xor(qv.y, off);
                    }
                    if (lane == 0) redS = qv;
                }
                __syncthreads();
                const float inva = 2.0f / redS.x;
                const float invb = 2.0f / redS.y;

                #pragma unroll
                for (int j = 0; j < 4; ++j) {
                    float4 lo, hi;
                    unpack8(cur[j], lo, hi);
                    const float c = e[j] * ((j < 2) ? inva : invb);
                    fma4(acc[(j & 1) * 2],     c, lo);
                    fma4(acc[(j & 1) * 2 + 1], c, hi);
                }

                #pragma unroll
                for (int j = 0; j < 4; ++j) cur[j] = nxt[j];
                p = pn;
            }

            float4* sp = reinterpret_cast<float4*>(part) + (size_t)blk * ROW_C4;
            sp[2 * u0]            = acc[0];
            sp[2 * u0 + 1]        = acc[1];
            sp[2 * (u0 + 64)]     = acc[2];
            sp[2 * (u0 + 64) + 1] = acc[3];
        }
        grid.sync();
    }
}

// ===========================================================================
// Fallback path: exact R6 separate kernels (proven 162 us).
// ===========================================================================
__global__ __launch_bounds__(1024) void k_uniform(const float* __restrict__ uh,
                                                  u16* __restrict__ uh2,
                                                  float* __restrict__ part) {
    const int t    = threadIdx.x;
    const int wave = t >> 6;
    const int lane = t & 63;
    const int c0   = (wave << 8) + lane;

    float4 acc[4];
    #pragma unroll
    for (int j = 0; j < 4; ++j) acc[j] = make_float4(0.f, 0.f, 0.f, 0.f);

    const float4* p = reinterpret_cast<const float4*>(uh)
                    + (size_t)blockIdx.x * PB * ROW_C4 + c0;
    ushort4* q = reinterpret_cast<ushort4*>(uh2)
               + (size_t)blockIdx.x * PB * ROW_C4 + c0;

    for (int g = 0; g < PB; ++g) {
        float4 u[4];
        #pragma unroll
        for (int j = 0; j < 4; ++j) u[j] = p[j * 64];
        #pragma unroll
        for (int j = 0; j < 4; ++j) { add4(acc[j], u[j]); q[j * 64] = f2b4(u[j]); }
        p += ROW_C4; q += ROW_C4;
    }

    const float c = 1.0f / OUT_NODES;
    float4* sp = reinterpret_cast<float4*>(part) + (size_t)blockIdx.x * ROW_C4 + c0;
    #pragma unroll
    for (int j = 0; j < 4; ++j) {
        acc[j].x *= c; acc[j].y *= c; acc[j].z *= c; acc[j].w *= c;
        sp[j * 64] = acc[j];
    }
}

__global__ __launch_bounds__(1024) void k_soft(const u16* __restrict__ uh2,
                                               const float* __restrict__ V,
                                               float* __restrict__ part) {
    const int t    = threadIdx.x;
    const int wave = t >> 6;
    const int lane = t & 63;
    const int u0   = (wave << 7) + lane;

    __shared__ float2 red16[16];
    __shared__ float2 redS;

    float4 v[4];
    {
        const float4* vp = reinterpret_cast<const float4*>(V);
        v[0] = vp[2 * u0];          v[1] = vp[2 * u0 + 1];
        v[2] = vp[2 * (u0 + 64)];   v[3] = vp[2 * (u0 + 64) + 1];
    }

    float4 acc[4];
    #pragma unroll
    for (int j = 0; j < 4; ++j) acc[j] = make_float4(0.f, 0.f, 0.f, 0.f);

    const uint4* p = reinterpret_cast<const uint4*>(uh2)
                   + (size_t)blockIdx.x * PB * ROW_U4 + u0;

    uint4 cur[4];
    cur[0] = p[0];      cur[1] = p[64];
    cur[2] = p[ROW_U4]; cur[3] = p[ROW_U4 + 64];

    for (int g = 0; g < PB; g += 2) {
        uint4 nxt[4];
        const uint4* pn = p + 2 * ROW_U4;
        if (g + 2 < PB) {
            nxt[0] = pn[0];      nxt[1] = pn[64];
            nxt[2] = pn[ROW_U4]; nxt[3] = pn[ROW_U4 + 64];
        }

        float d[4];
        #pragma unroll
        for (int j = 0; j < 4; ++j) {
            float4 lo, hi;
            unpack8(cur[j], lo, hi);
            d[j] = dot4(lo, v[(j & 1) * 2]) + dot4(hi, v[(j & 1) * 2 + 1]);
        }
        #pragma unroll
        for (int j = 0; j < 4; ++j) d[j] += __shfl_xor(d[j], 1);

        float e[4];
        #pragma unroll
        for (int j = 0; j < 4; ++j) e[j] = __expf(d[j]);

        float ea = e[0] + e[1];
        float eb = e[2] + e[3];
        #pragma unroll
        for (int off = 32; off; off >>= 1) {
            ea += __shfl_xor(ea, off);
            eb += __shfl_xor(eb, off);
        }
        if (lane == 0) red16[wave] = make_float2(ea, eb);
        __syncthreads();
        if (wave == 0) {
            float2 qv = (lane < 16) ? red16[lane] : make_float2(0.f, 0.f);
            #pragma unroll
            for (int off = 8; off; off >>= 1) {
                qv.x += __shfl_xor(qv.x, off);
                qv.y += __shfl_xor(qv.y, off);
            }
            if (lane == 0) redS = qv;
        }
        __syncthreads();
        const float inva = 2.0f / redS.x;
        const float invb = 2.0f / redS.y;

        #pragma unroll
        for (int j = 0; j < 4; ++j) {
            float4 lo, hi;
            unpack8(cur[j], lo, hi);
            const float c = e[j] * ((j < 2) ? inva : invb);
            fma4(acc[(j & 1) * 2],     c, lo);
            fma4(acc[(j & 1) * 2 + 1], c, hi);
        }

        #pragma unroll
        for (int j = 0; j < 4; ++j) cur[j] = nxt[j];
        p = pn;
    }

    float4* sp = reinterpret_cast<float4*>(part) + (size_t)blockIdx.x * ROW_C4;
    sp[2 * u0]            = acc[0];
    sp[2 * u0 + 1]        = acc[1];
    sp[2 * (u0 + 64)]     = acc[2];
    sp[2 * (u0 + 64) + 1] = acc[3];
}

__global__ __launch_bounds__(256) void k_reduce(const float* __restrict__ part,
                                                float* __restrict__ V,
                                                float* __restrict__ out,
                                                int G, int first) {
    const int t    = threadIdx.x;
    const int gidx = blockIdx.x * 64 + (t >> 2);   // o*16 + f
    const int q    = t & 3;
    const float* p = part + gidx;
    float a0 = 0.f, a1 = 0.f;
    int b = q;
    for (; b + 4 < G; b += 8) {
        a0 += p[(size_t)(b    ) * ROW_ELEMS];
        a1 += p[(size_t)(b + 4) * ROW_ELEMS];
    }
    for (; b < G; b += 4) a0 += p[(size_t)b * ROW_ELEMS];
    float s = a0 + a1;
    s += __shfl_xor(s, 1);
    s += __shfl_xor(s, 2);

    float sq = s * s;
    sq += __shfl_xor(sq, 4);
    sq += __shfl_xor(sq, 8);
    sq += __shfl_xor(sq, 16);
    sq += __shfl_xor(sq, 32);

    const float scale = sq / ((1.0f + sq) * sqrtf(sq));
    const float v = s * scale;

    out[gidx] = v;
    V[gidx]   = first ? v : (V[gidx] + v);
}

// ---------------------------------------------------------------------------
extern "C" void kernel_launch(void* const* d_in, const int* in_sizes, int n_in,
                              void* d_out, int out_size, void* d_ws, size_t ws_size,
                              hipStream_t stream) {
    const float* uh  = (const float*)d_in[0];
    float*       out = (float*)d_out;

    char*  ws   = (char*)d_ws;
    float* V    = (float*)ws;                              // 64 KB
    float* part = (float*)(ws + 65536);                    // 256*64KB = 16 MB
    u16*   uh2  = (u16*)(ws + 65536 + (size_t)NG * ROW_ELEMS * 4);  // 128 MB

    const size_t need = 65536ull + (size_t)NG * ROW_ELEMS * 4ull
                      + (size_t)IN_NODES * ROW_ELEMS * 2ull;

    bool ok = false;
    if (ws_size >= need) {
        void* args[] = { (void*)&uh, (void*)&uh2, (void*)&part,
                         (void*)&V, (void*)&out };
        hipError_t e = hipLaunchCooperativeKernel((const void*)fused_route,
                                                  dim3(NG), dim3(1024),
                                                  args, 0, stream);
        ok = (e == hipSuccess);
    }

    if (!ok && ws_size >= need) {
        // R6 separate-kernel path (proven)
        k_uniform<<<NG, 1024, 0, stream>>>(uh, uh2, part);
        k_reduce<<<256, 256, 0, stream>>>(part, V, out, NG, 1);
        for (int it = 1; it < 3; ++it) {
            k_soft<<<NG, 1024, 0, stream>>>(uh2, V, part);
            k_reduce<<<256, 256, 0, stream>>>(part, V, out, NG, 0);
        }
    }
}

// Round 10
// 162.222 us; speedup vs baseline: 2.0801x; 1.9083x over previous
//
#include <hip/hip_runtime.h>
#include <math.h>

#define IN_NODES  4096
#define OUT_NODES 1024
#define ROW_ELEMS 16384          // floats per in-node row
#define ROW_C4    4096           // float4 chunks per row
#define ROW_U4    2048           // uint4 (8xbf16) chunks per row
#define NG        256            // grid
#define PB        16             // rows per block (4096/256)

typedef unsigned short u16;
typedef unsigned int   u32;

__device__ __forceinline__ float dot4(const float4 a, const float4 b) {
    return a.x*b.x + a.y*b.y + a.z*b.z + a.w*b.w;
}
__device__ __forceinline__ void fma4(float4& a, const float c, const float4 u) {
    a.x += c*u.x; a.y += c*u.y; a.z += c*u.z; a.w += c*u.w;
}
__device__ __forceinline__ void add4(float4& a, const float4 u) {
    a.x += u.x; a.y += u.y; a.z += u.z; a.w += u.w;
}
__device__ __forceinline__ u16 f2b(float x) {            // RNE f32->bf16
    u32 b = __float_as_uint(x);
    return (u16)((b + 0x7FFFu + ((b >> 16) & 1u)) >> 16);
}
__device__ __forceinline__ ushort4 f2b4(float4 v) {
    ushort4 r; r.x = f2b(v.x); r.y = f2b(v.y); r.z = f2b(v.z); r.w = f2b(v.w);
    return r;
}
// uint4 = 8 bf16 (memory order) -> two float4
__device__ __forceinline__ void unpack8(const uint4 w, float4& lo, float4& hi) {
    lo.x = __uint_as_float(w.x << 16);
    lo.y = __uint_as_float(w.x & 0xFFFF0000u);
    lo.z = __uint_as_float(w.y << 16);
    lo.w = __uint_as_float(w.y & 0xFFFF0000u);
    hi.x = __uint_as_float(w.z << 16);
    hi.y = __uint_as_float(w.z & 0xFFFF0000u);
    hi.z = __uint_as_float(w.w << 16);
    hi.w = __uint_as_float(w.w & 0xFFFF0000u);
}

// ---------------------------------------------------------------------------
// K0: uniform pass (c = 1/1024) + bf16 copy. 256 blocks x 1024 thr
// (1 block/CU, 4 waves/EU declared), no barriers, ~45 VGPR, fully coalesced.
// Identical to the 162 us R6 kernel except the explicit min-waves spec.
// ---------------------------------------------------------------------------
__global__ __launch_bounds__(1024, 4) void k_uniform(const float* __restrict__ uh,
                                                     u16* __restrict__ uh2,
                                                     float* __restrict__ part) {
    const int t    = threadIdx.x;
    const int wave = t >> 6;
    const int lane = t & 63;
    const int c0   = (wave << 8) + lane;

    float4 acc[4];
    #pragma unroll
    for (int j = 0; j < 4; ++j) acc[j] = make_float4(0.f, 0.f, 0.f, 0.f);

    const float4* p = reinterpret_cast<const float4*>(uh)
                    + (size_t)blockIdx.x * PB * ROW_C4 + c0;
    ushort4* q = reinterpret_cast<ushort4*>(uh2)
               + (size_t)blockIdx.x * PB * ROW_C4 + c0;

    for (int g = 0; g < PB; ++g) {
        float4 u[4];
        #pragma unroll
        for (int j = 0; j < 4; ++j) u[j] = p[j * 64];
        #pragma unroll
        for (int j = 0; j < 4; ++j) { add4(acc[j], u[j]); q[j * 64] = f2b4(u[j]); }
        p += ROW_C4; q += ROW_C4;
    }

    const float c = 1.0f / OUT_NODES;
    float4* sp = reinterpret_cast<float4*>(part) + (size_t)blockIdx.x * ROW_C4 + c0;
    #pragma unroll
    for (int j = 0; j < 4; ++j) {
        acc[j].x *= c; acc[j].y *= c; acc[j].z *= c; acc[j].w *= c;
        sp[j * 64] = acc[j];
    }
}

// ---------------------------------------------------------------------------
// K_soft: softmax pass over the bf16 copy. 256 blocks x 1024 thr.
// __launch_bounds__(1024, 4) => register allocator may use up to 128 VGPR
// (1 block/CU) instead of the 64-VGPR heuristic that spilled the ~100 live
// values of this body (diagnosed from the R9 fused kernel's VGPR_Count=64,
// VALUBusy 7%). Body identical to the 162 us R6 kernel.
// ---------------------------------------------------------------------------
__global__ __launch_bounds__(1024, 4) void k_soft(const u16* __restrict__ uh2,
                                                  const float* __restrict__ V,
                                                  float* __restrict__ part) {
    const int t    = threadIdx.x;
    const int wave = t >> 6;
    const int lane = t & 63;
    const int u0   = (wave << 7) + lane;      // first uint4 unit (second +64)

    __shared__ float2 red16[16];
    __shared__ float2 redS;

    float4 v[4];
    {
        const float4* vp = reinterpret_cast<const float4*>(V);
        v[0] = vp[2 * u0];          v[1] = vp[2 * u0 + 1];
        v[2] = vp[2 * (u0 + 64)];   v[3] = vp[2 * (u0 + 64) + 1];
    }

    float4 acc[4];
    #pragma unroll
    for (int j = 0; j < 4; ++j) acc[j] = make_float4(0.f, 0.f, 0.f, 0.f);

    const uint4* p = reinterpret_cast<const uint4*>(uh2)
                   + (size_t)blockIdx.x * PB * ROW_U4 + u0;

    // cur = rows g, g+1 (units u0, u0+64 each)
    uint4 cur[4];
    cur[0] = p[0];      cur[1] = p[64];
    cur[2] = p[ROW_U4]; cur[3] = p[ROW_U4 + 64];

    for (int g = 0; g < PB; g += 2) {
        uint4 nxt[4];
        const uint4* pn = p + 2 * ROW_U4;
        if (g + 2 < PB) {
            nxt[0] = pn[0];      nxt[1] = pn[64];
            nxt[2] = pn[ROW_U4]; nxt[3] = pn[ROW_U4 + 64];
        }

        // dots (row a: cur[0],cur[1]; row b: cur[2],cur[3])
        float d[4];
        #pragma unroll
        for (int j = 0; j < 4; ++j) {
            float4 lo, hi;
            unpack8(cur[j], lo, hi);
            d[j] = dot4(lo, v[(j & 1) * 2]) + dot4(hi, v[(j & 1) * 2 + 1]);
        }
        #pragma unroll
        for (int j = 0; j < 4; ++j) d[j] += __shfl_xor(d[j], 1);

        float e[4];
        #pragma unroll
        for (int j = 0; j < 4; ++j) e[j] = __expf(d[j]);

        float ea = e[0] + e[1];       // row a partial denom (each o counted 2x)
        float eb = e[2] + e[3];       // row b
        #pragma unroll
        for (int off = 32; off; off >>= 1) {
            ea += __shfl_xor(ea, off);
            eb += __shfl_xor(eb, off);
        }
        if (lane == 0) red16[wave] = make_float2(ea, eb);
        __syncthreads();
        if (wave == 0) {
            float2 qv = (lane < 16) ? red16[lane] : make_float2(0.f, 0.f);
            #pragma unroll
            for (int off = 8; off; off >>= 1) {
                qv.x += __shfl_xor(qv.x, off);
                qv.y += __shfl_xor(qv.y, off);
            }
            if (lane == 0) redS = qv;
        }
        __syncthreads();
        const float inva = 2.0f / redS.x;
        const float invb = 2.0f / redS.y;

        // FMA phase: recompute unpack (keeps live state small)
        #pragma unroll
        for (int j = 0; j < 4; ++j) {
            float4 lo, hi;
            unpack8(cur[j], lo, hi);
            const float c = e[j] * ((j < 2) ? inva : invb);
            fma4(acc[(j & 1) * 2],     c, lo);
            fma4(acc[(j & 1) * 2 + 1], c, hi);
        }

        #pragma unroll
        for (int j = 0; j < 4; ++j) cur[j] = nxt[j];
        p = pn;
    }

    float4* sp = reinterpret_cast<float4*>(part) + (size_t)blockIdx.x * ROW_C4;
    sp[2 * u0]            = acc[0];
    sp[2 * u0 + 1]        = acc[1];
    sp[2 * (u0 + 64)]     = acc[2];
    sp[2 * (u0 + 64) + 1] = acc[3];
}

// ---------------------------------------------------------------------------
// Reduce partials -> s, squash -> v, out, cumulative V. (Unchanged from R6.)
// ---------------------------------------------------------------------------
__global__ __launch_bounds__(256) void k_reduce(const float* __restrict__ part,
                                                float* __restrict__ V,
                                                float* __restrict__ out,
                                                int G, int first) {
    const int t    = threadIdx.x;
    const int gidx = blockIdx.x * 64 + (t >> 2);   // o*16 + f
    const int q    = t & 3;
    const float* p = part + gidx;
    float a0 = 0.f, a1 = 0.f;
    int b = q;
    for (; b + 4 < G; b += 8) {
        a0 += p[(size_t)(b    ) * ROW_ELEMS];
        a1 += p[(size_t)(b + 4) * ROW_ELEMS];
    }
    for (; b < G; b += 4) a0 += p[(size_t)b * ROW_ELEMS];
    float s = a0 + a1;
    s += __shfl_xor(s, 1);
    s += __shfl_xor(s, 2);

    float sq = s * s;
    sq += __shfl_xor(sq, 4);
    sq += __shfl_xor(sq, 8);
    sq += __shfl_xor(sq, 16);
    sq += __shfl_xor(sq, 32);

    const float scale = sq / ((1.0f + sq) * sqrtf(sq));
    const float v = s * scale;

    out[gidx] = v;
    V[gidx]   = first ? v : (V[gidx] + v);
}

// ===========================================================================
// f32 fallback (only if workspace is unexpectedly small): R6-style kernels.
// ===========================================================================
__global__ __launch_bounds__(1024, 4) void fb_uniform(const float* __restrict__ uh,
                                                      float* __restrict__ part,
                                                      int per_block) {
    const int t  = threadIdx.x;
    const int c0 = ((t >> 6) << 8) + (t & 63);
    float4 acc[4];
    #pragma unroll
    for (int j = 0; j < 4; ++j) acc[j] = make_float4(0.f, 0.f, 0.f, 0.f);
    const float4* p = reinterpret_cast<const float4*>(uh)
                    + (size_t)blockIdx.x * per_block * ROW_C4 + c0;
    for (int g = 0; g < per_block; ++g) {
        #pragma unroll
        for (int j = 0; j < 4; ++j) add4(acc[j], p[j * 64]);
        p += ROW_C4;
    }
    const float c = 1.0f / OUT_NODES;
    float4* sp = reinterpret_cast<float4*>(part) + (size_t)blockIdx.x * ROW_C4 + c0;
    #pragma unroll
    for (int j = 0; j < 4; ++j) {
        acc[j].x *= c; acc[j].y *= c; acc[j].z *= c; acc[j].w *= c;
        sp[j * 64] = acc[j];
    }
}

__global__ __launch_bounds__(1024, 4) void fb_soft(const float* __restrict__ uh,
                                                   const float* __restrict__ V,
                                                   float* __restrict__ part,
                                                   int per_block) {
    const int t    = threadIdx.x;
    const int wave = t >> 6;
    const int lane = t & 63;
    const int c0   = (wave << 8) + lane;
    __shared__ float red16[16];
    __shared__ float redS;

    float4 v[4];
    const float4* vp = reinterpret_cast<const float4*>(V) + c0;
    #pragma unroll
    for (int j = 0; j < 4; ++j) v[j] = vp[j * 64];

    float4 acc[4];
    #pragma unroll
    for (int j = 0; j < 4; ++j) acc[j] = make_float4(0.f, 0.f, 0.f, 0.f);

    const float4* p = reinterpret_cast<const float4*>(uh)
                    + (size_t)blockIdx.x * per_block * ROW_C4 + c0;
    for (int g = 0; g < per_block; ++g) {
        float4 u[4];
        #pragma unroll
        for (int j = 0; j < 4; ++j) u[j] = p[j * 64];
        float d[4];
        #pragma unroll
        for (int j = 0; j < 4; ++j) d[j] = dot4(u[j], v[j]);
        #pragma unroll
        for (int j = 0; j < 4; ++j) {
            d[j] += __shfl_xor(d[j], 1);
            d[j] += __shfl_xor(d[j], 2);
        }
        float e[4];
        float etot = 0.f;
        #pragma unroll
        for (int j = 0; j < 4; ++j) { e[j] = __expf(d[j]); etot += e[j]; }
        #pragma unroll
        for (int off = 32; off; off >>= 1) etot += __shfl_xor(etot, off);
        if (lane == 0) red16[wave] = etot;
        __syncthreads();
        if (wave == 0) {
            float s = (lane < 16) ? red16[lane] : 0.f;
            #pragma unroll
            for (int off = 8; off; off >>= 1) s += __shfl_xor(s, off);
            if (lane == 0) redS = s;
        }
        __syncthreads();
        const float inv = 4.0f / redS;
        #pragma unroll
        for (int j = 0; j < 4; ++j) fma4(acc[j], e[j] * inv, u[j]);
        p += ROW_C4;
    }
    float4* sp = reinterpret_cast<float4*>(part) + (size_t)blockIdx.x * ROW_C4 + c0;
    #pragma unroll
    for (int j = 0; j < 4; ++j) sp[j * 64] = acc[j];
}

// ---------------------------------------------------------------------------
extern "C" void kernel_launch(void* const* d_in, const int* in_sizes, int n_in,
                              void* d_out, int out_size, void* d_ws, size_t ws_size,
                              hipStream_t stream) {
    const float* uh  = (const float*)d_in[0];
    float*       out = (float*)d_out;

    char*  ws   = (char*)d_ws;
    float* V    = (float*)ws;                              // 64 KB
    float* part = (float*)(ws + 65536);                    // 256*64KB = 16 MB
    u16*   uh2  = (u16*)(ws + 65536 + (size_t)NG * ROW_ELEMS * 4);  // 128 MB

    const size_t need = 65536ull + (size_t)NG * ROW_ELEMS * 4ull
                      + (size_t)IN_NODES * ROW_ELEMS * 2ull;

    if (ws_size >= need) {
        k_uniform<<<NG, 1024, 0, stream>>>(uh, uh2, part);
        k_reduce<<<256, 256, 0, stream>>>(part, V, out, NG, 1);
        for (int it = 1; it < 3; ++it) {
            k_soft<<<NG, 1024, 0, stream>>>(uh2, V, part);
            k_reduce<<<256, 256, 0, stream>>>(part, V, out, NG, 0);
        }
    } else {
        int G2 = 256;
        while (G2 > 4 && ws_size < 65536ull * (size_t)(G2 + 1)) G2 >>= 1;
        const int per_block = IN_NODES / G2;
        fb_uniform<<<G2, 1024, 0, stream>>>(uh, part, per_block);
        k_reduce<<<256, 256, 0, stream>>>(part, V, out, G2, 1);
        for (int it = 1; it < 3; ++it) {
            fb_soft<<<G2, 1024, 0, stream>>>(uh, V, part, per_block);
            k_reduce<<<256, 256, 0, stream>>>(part, V, out, G2, 0);
        }
    }
}

// Round 11
// 158.244 us; speedup vs baseline: 2.1324x; 1.0251x over previous
//
#include <hip/hip_runtime.h>
#include <math.h>

#define IN_NODES  4096
#define OUT_NODES 1024
#define ROW_ELEMS 16384          // elems per in-node row (1024*16)
#define ROW_C4    4096           // 4-elem chunks per row
#define ROW_U4    2048           // uint4 (8xbf16) chunks per row
#define NG        256            // grid
#define PB        16             // rows per block (4096/256)

typedef unsigned short u16;
typedef unsigned int   u32;

__device__ __forceinline__ float dot4(const float4 a, const float4 b) {
    return a.x*b.x + a.y*b.y + a.z*b.z + a.w*b.w;
}
__device__ __forceinline__ void fma4(float4& a, const float c, const float4 u) {
    a.x += c*u.x; a.y += c*u.y; a.z += c*u.z; a.w += c*u.w;
}
__device__ __forceinline__ void add4(float4& a, const float4 u) {
    a.x += u.x; a.y += u.y; a.z += u.z; a.w += u.w;
}
__device__ __forceinline__ float b2f1(u16 u) {
    return __uint_as_float(((u32)u) << 16);
}
__device__ __forceinline__ u16 f2b(float x) {            // RNE f32->bf16
    u32 b = __float_as_uint(x);
    return (u16)((b + 0x7FFFu + ((b >> 16) & 1u)) >> 16);
}
__device__ __forceinline__ ushort4 f2b4(float4 v) {
    ushort4 r; r.x = f2b(v.x); r.y = f2b(v.y); r.z = f2b(v.z); r.w = f2b(v.w);
    return r;
}
// uint4 = 8 bf16 (memory order) -> two float4
__device__ __forceinline__ void unpack8(const uint4 w, float4& lo, float4& hi) {
    lo.x = __uint_as_float(w.x << 16);
    lo.y = __uint_as_float(w.x & 0xFFFF0000u);
    lo.z = __uint_as_float(w.y << 16);
    lo.w = __uint_as_float(w.y & 0xFFFF0000u);
    hi.x = __uint_as_float(w.z << 16);
    hi.y = __uint_as_float(w.z & 0xFFFF0000u);
    hi.z = __uint_as_float(w.w << 16);
    hi.w = __uint_as_float(w.w & 0xFFFF0000u);
}

// ---------------------------------------------------------------------------
// K0: uniform pass (c = 1/1024) + bf16 copy of u_hat. 256 blocks x 1024 thr,
// no barriers, fully coalesced. Identical to the 162 us R6/R10 kernel except
// the partial-s store is now bf16 (halves that stream).
// ---------------------------------------------------------------------------
__global__ __launch_bounds__(1024, 4) void k_uniform(const float* __restrict__ uh,
                                                     u16* __restrict__ uh2,
                                                     u16* __restrict__ part) {
    const int t    = threadIdx.x;
    const int wave = t >> 6;
    const int lane = t & 63;
    const int c0   = (wave << 8) + lane;

    float4 acc[4];
    #pragma unroll
    for (int j = 0; j < 4; ++j) acc[j] = make_float4(0.f, 0.f, 0.f, 0.f);

    const float4* p = reinterpret_cast<const float4*>(uh)
                    + (size_t)blockIdx.x * PB * ROW_C4 + c0;
    ushort4* q = reinterpret_cast<ushort4*>(uh2)
               + (size_t)blockIdx.x * PB * ROW_C4 + c0;

    for (int g = 0; g < PB; ++g) {
        float4 u[4];
        #pragma unroll
        for (int j = 0; j < 4; ++j) u[j] = p[j * 64];
        #pragma unroll
        for (int j = 0; j < 4; ++j) { add4(acc[j], u[j]); q[j * 64] = f2b4(u[j]); }
        p += ROW_C4; q += ROW_C4;
    }

    const float c = 1.0f / OUT_NODES;
    ushort4* sp = reinterpret_cast<ushort4*>(part) + (size_t)blockIdx.x * ROW_C4 + c0;
    #pragma unroll
    for (int j = 0; j < 4; ++j) {
        acc[j].x *= c; acc[j].y *= c; acc[j].z *= c; acc[j].w *= c;
        sp[j * 64] = f2b4(acc[j]);
    }
}

// ---------------------------------------------------------------------------
// K_soft: softmax pass over the bf16 copy. Body identical to the proven
// R6/R10 kernel; only the partial-s store is bf16 now.
// ---------------------------------------------------------------------------
__global__ __launch_bounds__(1024, 4) void k_soft(const u16* __restrict__ uh2,
                                                  const float* __restrict__ V,
                                                  u16* __restrict__ part) {
    const int t    = threadIdx.x;
    const int wave = t >> 6;
    const int lane = t & 63;
    const int u0   = (wave << 7) + lane;      // first uint4 unit (second +64)

    __shared__ float2 red16[16];
    __shared__ float2 redS;

    float4 v[4];
    {
        const float4* vp = reinterpret_cast<const float4*>(V);
        v[0] = vp[2 * u0];          v[1] = vp[2 * u0 + 1];
        v[2] = vp[2 * (u0 + 64)];   v[3] = vp[2 * (u0 + 64) + 1];
    }

    float4 acc[4];
    #pragma unroll
    for (int j = 0; j < 4; ++j) acc[j] = make_float4(0.f, 0.f, 0.f, 0.f);

    const uint4* p = reinterpret_cast<const uint4*>(uh2)
                   + (size_t)blockIdx.x * PB * ROW_U4 + u0;

    // cur = rows g, g+1 (units u0, u0+64 each)
    uint4 cur[4];
    cur[0] = p[0];      cur[1] = p[64];
    cur[2] = p[ROW_U4]; cur[3] = p[ROW_U4 + 64];

    for (int g = 0; g < PB; g += 2) {
        uint4 nxt[4];
        const uint4* pn = p + 2 * ROW_U4;
        if (g + 2 < PB) {
            nxt[0] = pn[0];      nxt[1] = pn[64];
            nxt[2] = pn[ROW_U4]; nxt[3] = pn[ROW_U4 + 64];
        }

        // dots (row a: cur[0],cur[1]; row b: cur[2],cur[3])
        float d[4];
        #pragma unroll
        for (int j = 0; j < 4; ++j) {
            float4 lo, hi;
            unpack8(cur[j], lo, hi);
            d[j] = dot4(lo, v[(j & 1) * 2]) + dot4(hi, v[(j & 1) * 2 + 1]);
        }
        #pragma unroll
        for (int j = 0; j < 4; ++j) d[j] += __shfl_xor(d[j], 1);

        float e[4];
        #pragma unroll
        for (int j = 0; j < 4; ++j) e[j] = __expf(d[j]);

        float ea = e[0] + e[1];       // row a partial denom (each o counted 2x)
        float eb = e[2] + e[3];       // row b
        #pragma unroll
        for (int off = 32; off; off >>= 1) {
            ea += __shfl_xor(ea, off);
            eb += __shfl_xor(eb, off);
        }
        if (lane == 0) red16[wave] = make_float2(ea, eb);
        __syncthreads();
        if (wave == 0) {
            float2 qv = (lane < 16) ? red16[lane] : make_float2(0.f, 0.f);
            #pragma unroll
            for (int off = 8; off; off >>= 1) {
                qv.x += __shfl_xor(qv.x, off);
                qv.y += __shfl_xor(qv.y, off);
            }
            if (lane == 0) redS = qv;
        }
        __syncthreads();
        const float inva = 2.0f / redS.x;
        const float invb = 2.0f / redS.y;

        // FMA phase: recompute unpack (keeps live state small)
        #pragma unroll
        for (int j = 0; j < 4; ++j) {
            float4 lo, hi;
            unpack8(cur[j], lo, hi);
            const float c = e[j] * ((j < 2) ? inva : invb);
            fma4(acc[(j & 1) * 2],     c, lo);
            fma4(acc[(j & 1) * 2 + 1], c, hi);
        }

        #pragma unroll
        for (int j = 0; j < 4; ++j) cur[j] = nxt[j];
        p = pn;
    }

    ushort4* sp = reinterpret_cast<ushort4*>(part) + (size_t)blockIdx.x * ROW_C4;
    sp[2 * u0]            = f2b4(acc[0]);
    sp[2 * u0 + 1]        = f2b4(acc[1]);
    sp[2 * (u0 + 64)]     = f2b4(acc[2]);
    sp[2 * (u0 + 64) + 1] = f2b4(acc[3]);
}

// ---------------------------------------------------------------------------
// Reduce bf16 partials -> s (f32), squash -> v, out, cumulative V.
// Same structure as the proven kernel; loads are 2B bf16 now (half bytes).
// ---------------------------------------------------------------------------
__global__ __launch_bounds__(256) void k_reduce(const u16* __restrict__ part,
                                                float* __restrict__ V,
                                                float* __restrict__ out,
                                                int G, int first) {
    const int t    = threadIdx.x;
    const int gidx = blockIdx.x * 64 + (t >> 2);   // o*16 + f
    const int q    = t & 3;
    const u16* p = part + gidx;
    float a0 = 0.f, a1 = 0.f;
    int b = q;
    for (; b + 4 < G; b += 8) {
        a0 += b2f1(p[(size_t)(b    ) * ROW_ELEMS]);
        a1 += b2f1(p[(size_t)(b + 4) * ROW_ELEMS]);
    }
    for (; b < G; b += 4) a0 += b2f1(p[(size_t)b * ROW_ELEMS]);
    float s = a0 + a1;
    s += __shfl_xor(s, 1);
    s += __shfl_xor(s, 2);

    float sq = s * s;
    sq += __shfl_xor(sq, 4);
    sq += __shfl_xor(sq, 8);
    sq += __shfl_xor(sq, 16);
    sq += __shfl_xor(sq, 32);

    const float scale = sq / ((1.0f + sq) * sqrtf(sq));
    const float v = s * scale;

    out[gidx] = v;
    V[gidx]   = first ? v : (V[gidx] + v);
}

// ===========================================================================
// f32-input fallback (only if workspace is unexpectedly small). Uses the
// same bf16 partial buffers + k_reduce.
// ===========================================================================
__global__ __launch_bounds__(1024, 4) void fb_uniform(const float* __restrict__ uh,
                                                      u16* __restrict__ part,
                                                      int per_block) {
    const int t  = threadIdx.x;
    const int c0 = ((t >> 6) << 8) + (t & 63);
    float4 acc[4];
    #pragma unroll
    for (int j = 0; j < 4; ++j) acc[j] = make_float4(0.f, 0.f, 0.f, 0.f);
    const float4* p = reinterpret_cast<const float4*>(uh)
                    + (size_t)blockIdx.x * per_block * ROW_C4 + c0;
    for (int g = 0; g < per_block; ++g) {
        #pragma unroll
        for (int j = 0; j < 4; ++j) add4(acc[j], p[j * 64]);
        p += ROW_C4;
    }
    const float c = 1.0f / OUT_NODES;
    ushort4* sp = reinterpret_cast<ushort4*>(part) + (size_t)blockIdx.x * ROW_C4 + c0;
    #pragma unroll
    for (int j = 0; j < 4; ++j) {
        acc[j].x *= c; acc[j].y *= c; acc[j].z *= c; acc[j].w *= c;
        sp[j * 64] = f2b4(acc[j]);
    }
}

__global__ __launch_bounds__(1024, 4) void fb_soft(const float* __restrict__ uh,
                                                   const float* __restrict__ V,
                                                   u16* __restrict__ part,
                                                   int per_block) {
    const int t    = threadIdx.x;
    const int wave = t >> 6;
    const int lane = t & 63;
    const int c0   = (wave << 8) + lane;
    __shared__ float red16[16];
    __shared__ float redS;

    float4 v[4];
    const float4* vp = reinterpret_cast<const float4*>(V) + c0;
    #pragma unroll
    for (int j = 0; j < 4; ++j) v[j] = vp[j * 64];

    float4 acc[4];
    #pragma unroll
    for (int j = 0; j < 4; ++j) acc[j] = make_float4(0.f, 0.f, 0.f, 0.f);

    const float4* p = reinterpret_cast<const float4*>(uh)
                    + (size_t)blockIdx.x * per_block * ROW_C4 + c0;
    for (int g = 0; g < per_block; ++g) {
        float4 u[4];
        #pragma unroll
        for (int j = 0; j < 4; ++j) u[j] = p[j * 64];
        float d[4];
        #pragma unroll
        for (int j = 0; j < 4; ++j) d[j] = dot4(u[j], v[j]);
        #pragma unroll
        for (int j = 0; j < 4; ++j) {
            d[j] += __shfl_xor(d[j], 1);
            d[j] += __shfl_xor(d[j], 2);
        }
        float e[4];
        float etot = 0.f;
        #pragma unroll
        for (int j = 0; j < 4; ++j) { e[j] = __expf(d[j]); etot += e[j]; }
        #pragma unroll
        for (int off = 32; off; off >>= 1) etot += __shfl_xor(etot, off);
        if (lane == 0) red16[wave] = etot;
        __syncthreads();
        if (wave == 0) {
            float s = (lane < 16) ? red16[lane] : 0.f;
            #pragma unroll
            for (int off = 8; off; off >>= 1) s += __shfl_xor(s, off);
            if (lane == 0) redS = s;
        }
        __syncthreads();
        const float inv = 4.0f / redS;
        #pragma unroll
        for (int j = 0; j < 4; ++j) fma4(acc[j], e[j] * inv, u[j]);
        p += ROW_C4;
    }
    ushort4* sp = reinterpret_cast<ushort4*>(part) + (size_t)blockIdx.x * ROW_C4 + c0;
    #pragma unroll
    for (int j = 0; j < 4; ++j) sp[j * 64] = f2b4(acc[j]);
}

// ---------------------------------------------------------------------------
extern "C" void kernel_launch(void* const* d_in, const int* in_sizes, int n_in,
                              void* d_out, int out_size, void* d_ws, size_t ws_size,
                              hipStream_t stream) {
    const float* uh  = (const float*)d_in[0];
    float*       out = (float*)d_out;

    // ws layout: V (64 KB f32) | part (256 * 32 KB bf16 = 8 MB) | uh2 (128 MB)
    char*  ws   = (char*)d_ws;
    float* V    = (float*)ws;
    u16*   part = (u16*)(ws + 65536);
    u16*   uh2  = (u16*)(ws + 65536 + (size_t)NG * ROW_ELEMS * 2);

    const size_t need = 65536ull + (size_t)NG * ROW_ELEMS * 2ull
                      + (size_t)IN_NODES * ROW_ELEMS * 2ull;

    if (ws_size >= need) {
        k_uniform<<<NG, 1024, 0, stream>>>(uh, uh2, part);
        k_reduce<<<256, 256, 0, stream>>>(part, V, out, NG, 1);
        for (int it = 1; it < 3; ++it) {
            k_soft<<<NG, 1024, 0, stream>>>(uh2, V, part);
            k_reduce<<<256, 256, 0, stream>>>(part, V, out, NG, 0);
        }
    } else {
        int G2 = 256;
        while (G2 > 4 && ws_size < 65536ull + 32768ull * (size_t)G2) G2 >>= 1;
        const int per_block = IN_NODES / G2;
        fb_uniform<<<G2, 1024, 0, stream>>>(uh, part, per_block);
        k_reduce<<<256, 256, 0, stream>>>(part, V, out, G2, 1);
        for (int it = 1; it < 3; ++it) {
            fb_soft<<<G2, 1024, 0, stream>>>(uh, V, part, per_block);
            k_reduce<<<256, 256, 0, stream>>>(part, V, out, G2, 0);
        }
    }
}